// Round 4
// baseline (782.077 us; speedup 1.0000x reference)
//
#include <hip/hip_runtime.h>
#include <hip/hip_bf16.h>

// adLIF: Wx = x @ W^T (fp32 FMA GEMM, strictly sequential-K accumulation to
// mirror BLAS bit-for-bit), then sequential LIF scan over T with rounding-exact
// fp32 ops. Input dtype (fp32 vs bf16) detected ON DEVICE from x's bit pattern.
// GEMM: 128x128 tile, 8x8 micro (VGPR~116 -> 4 waves/SIMD), KS=16,
// DOUBLE-BUFFERED padded LDS -> ONE barrier per K-chunk.
// Scan: 512 blocks x 128 thr, 64-t chunks via global_load_lds, double-buffered.

#define M_SZ 65536  // B*T
#define H_SZ 512
#define K_SZ 512
#define B_SZ 128
#define T_SZ 512
#define LSTR 132     // LDS row stride (dwords), %32==4: staging writes & reads ~conflict-free
#define LBUF (16 * LSTR)

__device__ __forceinline__ bool detect_bf16(const unsigned int* __restrict__ w) {
  int c = 0;
#pragma unroll
  for (int i = 0; i < 64; ++i) {
    unsigned int e = (w[i] >> 7) & 0xffu;
    c += (e >= 115u && e <= 131u) ? 1 : 0;
  }
  return c > 32;  // bf16 exponents cluster in [115,131]; fp32 mantissa bits don't
}

template <bool ISB>
__device__ __forceinline__ float4 ld4t(const void* __restrict__ p, size_t off) {
  if constexpr (!ISB) {
    return *reinterpret_cast<const float4*>(reinterpret_cast<const float*>(p) + off);
  } else {
    uint2 v = *reinterpret_cast<const uint2*>(reinterpret_cast<const unsigned short*>(p) + off);
    float4 r;
    r.x = __uint_as_float((v.x & 0xffffu) << 16);
    r.y = __uint_as_float(v.x & 0xffff0000u);
    r.z = __uint_as_float((v.y & 0xffffu) << 16);
    r.w = __uint_as_float(v.y & 0xffff0000u);
    return r;
  }
}

template <bool ISB>
__device__ __forceinline__ float ld1t(const void* __restrict__ p, int i) {
  if constexpr (!ISB) return reinterpret_cast<const float*>(p)[i];
  return __uint_as_float((unsigned int)(reinterpret_cast<const unsigned short*>(p)[i]) << 16);
}

__device__ __forceinline__ void gl_lds16(const void* g, void* l) {
  __builtin_amdgcn_global_load_lds(
      (const __attribute__((address_space(1))) void*)g,
      (__attribute__((address_space(3))) void*)l, 16, 0, 0);
}

// ---------------- GEMM: C[m][n] = sum_k X[m][k]*W[n][k], fp32, k ascending ----
template <bool ISB>
__device__ __forceinline__ void gemm_body(const void* __restrict__ X,
                                          const void* __restrict__ Wm,
                                          float* __restrict__ C,
                                          float* __restrict__ As,
                                          float* __restrict__ Bs) {
  const int tid = threadIdx.x;
  const int r0 = tid >> 2;       // 0..63: staged row
  const int q0 = (tid & 3) * 4;  // 0,4,8,12: k-group
  const int tx = tid & 15;       // n-group
  const int ty = tid >> 4;       // m-group
  const size_t M0 = (size_t)(blockIdx.x >> 2) * 128;
  const int N0 = (blockIdx.x & 3) * 128;

  float acc[8][8];
#pragma unroll
  for (int i = 0; i < 8; ++i)
#pragma unroll
    for (int j = 0; j < 8; ++j) acc[i][j] = 0.0f;

  const size_t aoff0 = (M0 + r0) * K_SZ + q0;
  const size_t aoff1 = (M0 + r0 + 64) * K_SZ + q0;
  const size_t boff0 = (size_t)(N0 + r0) * K_SZ + q0;
  const size_t boff1 = (size_t)(N0 + r0 + 64) * K_SZ + q0;

  float4 pa0 = ld4t<ISB>(X, aoff0), pa1 = ld4t<ISB>(X, aoff1);
  float4 pb0 = ld4t<ISB>(Wm, boff0), pb1 = ld4t<ISB>(Wm, boff1);

  // write chunk 0 into buffer 0
  {
    float* wa = As;
    float* wb = Bs;
    wa[(q0 + 0) * LSTR + r0] = pa0.x; wa[(q0 + 1) * LSTR + r0] = pa0.y;
    wa[(q0 + 2) * LSTR + r0] = pa0.z; wa[(q0 + 3) * LSTR + r0] = pa0.w;
    wa[(q0 + 0) * LSTR + r0 + 64] = pa1.x; wa[(q0 + 1) * LSTR + r0 + 64] = pa1.y;
    wa[(q0 + 2) * LSTR + r0 + 64] = pa1.z; wa[(q0 + 3) * LSTR + r0 + 64] = pa1.w;
    wb[(q0 + 0) * LSTR + r0] = pb0.x; wb[(q0 + 1) * LSTR + r0] = pb0.y;
    wb[(q0 + 2) * LSTR + r0] = pb0.z; wb[(q0 + 3) * LSTR + r0] = pb0.w;
    wb[(q0 + 0) * LSTR + r0 + 64] = pb1.x; wb[(q0 + 1) * LSTR + r0 + 64] = pb1.y;
    wb[(q0 + 2) * LSTR + r0 + 64] = pb1.z; wb[(q0 + 3) * LSTR + r0 + 64] = pb1.w;
  }

  const int NC = K_SZ / 16;  // 32 chunks
  for (int c = 0; c < NC; ++c) {
    __syncthreads();  // buf[c&1] writes visible; no global loads pending here
    if (c + 1 < NC) {  // prefetch chunk c+1 (in flight across compute)
      const int kk = (c + 1) * 16;
      pa0 = ld4t<ISB>(X, aoff0 + kk); pa1 = ld4t<ISB>(X, aoff1 + kk);
      pb0 = ld4t<ISB>(Wm, boff0 + kk); pb1 = ld4t<ISB>(Wm, boff1 + kk);
    }
    const float* ab = As + (c & 1) * LBUF;
    const float* bbk = Bs + (c & 1) * LBUF;
#pragma unroll
    for (int k = 0; k < 16; ++k) {
      const float4 a0 = *reinterpret_cast<const float4*>(ab + k * LSTR + ty * 4);
      const float4 a1 = *reinterpret_cast<const float4*>(ab + k * LSTR + 64 + ty * 4);
      const float4 b0 = *reinterpret_cast<const float4*>(bbk + k * LSTR + tx * 4);
      const float4 b1 = *reinterpret_cast<const float4*>(bbk + k * LSTR + 64 + tx * 4);
      const float av[8] = {a0.x, a0.y, a0.z, a0.w, a1.x, a1.y, a1.z, a1.w};
      const float bv[8] = {b0.x, b0.y, b0.z, b0.w, b1.x, b1.y, b1.z, b1.w};
#pragma unroll
      for (int i = 0; i < 8; ++i)
#pragma unroll
        for (int j = 0; j < 8; ++j) acc[i][j] += av[i] * bv[j];  // contracts to FMA
    }
    if (c + 1 < NC) {  // stage chunk c+1 into the other buffer (no barrier needed)
      float* wa = As + ((c + 1) & 1) * LBUF;
      float* wb = Bs + ((c + 1) & 1) * LBUF;
      wa[(q0 + 0) * LSTR + r0] = pa0.x; wa[(q0 + 1) * LSTR + r0] = pa0.y;
      wa[(q0 + 2) * LSTR + r0] = pa0.z; wa[(q0 + 3) * LSTR + r0] = pa0.w;
      wa[(q0 + 0) * LSTR + r0 + 64] = pa1.x; wa[(q0 + 1) * LSTR + r0 + 64] = pa1.y;
      wa[(q0 + 2) * LSTR + r0 + 64] = pa1.z; wa[(q0 + 3) * LSTR + r0 + 64] = pa1.w;
      wb[(q0 + 0) * LSTR + r0] = pb0.x; wb[(q0 + 1) * LSTR + r0] = pb0.y;
      wb[(q0 + 2) * LSTR + r0] = pb0.z; wb[(q0 + 3) * LSTR + r0] = pb0.w;
      wb[(q0 + 0) * LSTR + r0 + 64] = pb1.x; wb[(q0 + 1) * LSTR + r0 + 64] = pb1.y;
      wb[(q0 + 2) * LSTR + r0 + 64] = pb1.z; wb[(q0 + 3) * LSTR + r0 + 64] = pb1.w;
    }
  }

#pragma unroll
  for (int r = 0; r < 8; ++r) {
    const size_t m = M0 + ((r < 4) ? (ty * 4 + r) : (64 + ty * 4 + (r - 4)));
    float* Cp = C + m * H_SZ + N0;
    float4 v0 = {acc[r][0], acc[r][1], acc[r][2], acc[r][3]};
    float4 v1 = {acc[r][4], acc[r][5], acc[r][6], acc[r][7]};
    *reinterpret_cast<float4*>(Cp + tx * 4) = v0;
    *reinterpret_cast<float4*>(Cp + 64 + tx * 4) = v1;
  }
}

__global__ __launch_bounds__(256) void sgemm_bt(const void* __restrict__ X,
                                                const void* __restrict__ Wm,
                                                float* __restrict__ C) {
  __shared__ float As[2 * LBUF];  // 16.9 KB
  __shared__ float Bs[2 * LBUF];  // 16.9 KB
  if (detect_bf16(reinterpret_cast<const unsigned int*>(X)))
    gemm_body<true>(X, Wm, C, As, Bs);
  else
    gemm_body<false>(X, Wm, C, As, Bs);
}

// ---------------- LIF scan: 512 blocks x 128 thr, 64-t chunks, double-buffer --
#define SCH 64  // timesteps per chunk

template <bool ISB>
__device__ __forceinline__ void scan_body(
    const float* __restrict__ wx, const void* __restrict__ alpha_p,
    const void* __restrict__ beta_p, const void* __restrict__ a_p,
    const void* __restrict__ b_p, const void* __restrict__ u0p,
    const void* __restrict__ w0p, const void* __restrict__ s0p,
    void* __restrict__ out, float* __restrict__ buf) {
  const int tid = threadIdx.x;      // 0..127
  const int wave = tid >> 6;        // 0/1
  const int lane = tid & 63;
  const int bb = blockIdx.x >> 2;
  const int quarter = blockIdx.x & 3;
  const int h = quarter * 128 + tid;

  const float al = fminf(fmaxf(ld1t<ISB>(alpha_p, h), (float)0.8187307530779818),
                         (float)0.9607894391523232);
  const float be = fminf(fmaxf(ld1t<ISB>(beta_p, h), (float)0.9672161004820059),
                         (float)0.9917013044213351);
  const float av = fminf(fmaxf(ld1t<ISB>(a_p, h), -1.0f), 1.0f);
  const float bv = fminf(fmaxf(ld1t<ISB>(b_p, h), 0.0f), 2.0f);
  const float om = __fsub_rn(1.0f, al);

  const int bh = bb * H_SZ + h;
  float u = ld1t<ISB>(u0p, bh);
  float w = ld1t<ISB>(w0p, bh);
  float s = ld1t<ISB>(s0p, bh);

  const float* xb = wx + (size_t)bb * T_SZ * H_SZ + quarter * 128;  // + t*H
  float* outf = reinterpret_cast<float*>(out);
  __hip_bfloat16* outb = reinterpret_cast<__hip_bfloat16*>(out);
  const size_t ob0 = (size_t)bb * T_SZ * H_SZ + h;

  // chunk c = timesteps c*64..c*64+63; 32 DMA instrs (16/wave), 1 KB each.
  // instr j covers chunk dwords j*256..j*256+255 (2 t-rows of 128 h).
  auto issue = [&](int c) {
    float* dst = buf + (c & 1) * (SCH * 128);
    const float* sp = xb + (size_t)c * SCH * H_SZ;
    const int t_sub = lane >> 5;           // 0/1
    const int h_off = (lane & 31) * 4;
#pragma unroll
    for (int i = 0; i < 16; ++i) {
      const int j = wave * 16 + i;
      gl_lds16(sp + (size_t)(2 * j + t_sub) * H_SZ + h_off, dst + j * 256 + lane * 4);
    }
  };

  issue(0);
  const int NCH = T_SZ / SCH;  // 8
  for (int c = 0; c < NCH; ++c) {
    __syncthreads();  // drains chunk-c DMA; guards buffer reuse
    if (c + 1 < NCH) issue(c + 1);  // in flight over this chunk's compute
    const float* cb = buf + (c & 1) * (SCH * 128);
#pragma unroll 16
    for (int j = 0; j < SCH; ++j) {
      const float cur = cb[j * 128 + tid];
      // numpy left-to-right, each op individually rounded (no FMA contraction)
      w = __fadd_rn(__fadd_rn(__fmul_rn(be, w), __fmul_rn(av, u)), __fmul_rn(bv, s));
      u = __fadd_rn(__fmul_rn(al, __fsub_rn(u, s)), __fmul_rn(om, __fsub_rn(cur, w)));
      s = (u > 1.0f) ? 1.0f : 0.0f;
      const size_t o = ob0 + (size_t)(c * SCH + j) * H_SZ;
      if constexpr (ISB) outb[o] = __float2bfloat16(s);  // 0/1 exact in bf16
      else outf[o] = s;
    }
  }
}

__global__ __launch_bounds__(128) void lif_scan(
    const float* __restrict__ wx, const void* __restrict__ X,
    const void* __restrict__ alpha_p, const void* __restrict__ beta_p,
    const void* __restrict__ a_p, const void* __restrict__ b_p,
    const void* __restrict__ u0p, const void* __restrict__ w0p,
    const void* __restrict__ s0p, void* __restrict__ out) {
  __shared__ float buf[2 * SCH * 128];  // 64 KB double buffer
  if (detect_bf16(reinterpret_cast<const unsigned int*>(X)))
    scan_body<true>(wx, alpha_p, beta_p, a_p, b_p, u0p, w0p, s0p, out, buf);
  else
    scan_body<false>(wx, alpha_p, beta_p, a_p, b_p, u0p, w0p, s0p, out, buf);
}

extern "C" void kernel_launch(void* const* d_in, const int* in_sizes, int n_in,
                              void* d_out, int out_size, void* d_ws, size_t ws_size,
                              hipStream_t stream) {
  const void* X = d_in[0];   // x [B,T,I]
  const void* Wm = d_in[1];  // W [H,I]
  float* ws = reinterpret_cast<float*>(d_ws);  // Wx fp32 [B,T,H]

  sgemm_bt<<<dim3((M_SZ / 128) * (H_SZ / 128)), dim3(256), 0, stream>>>(X, Wm, ws);

  lif_scan<<<dim3(B_SZ * 4), dim3(128), 0, stream>>>(
      ws, X, d_in[2], d_in[3], d_in[4], d_in[5], d_in[6], d_in[7], d_in[8], d_out);
}

// Round 6
// 649.949 us; speedup vs baseline: 1.2033x; 1.2033x over previous
//
#include <hip/hip_runtime.h>
#include <hip/hip_bf16.h>

// adLIF: Wx = x @ W^T (fp32 FMA GEMM, strictly sequential-K accumulation to
// mirror BLAS bit-for-bit), then sequential LIF scan over T with rounding-exact
// fp32 ops. Input dtype (fp32 vs bf16) detected ON DEVICE from x's bit pattern.
// GEMM: r2 structure (128x128 tile, 8x8 micro, VGPR~116) + LSTR=132 padding +
//       nontemporal C stores.
// Scan: barrier-free wave-autonomous pipeline: per-wave DMA ring (6 SG x 8t),
//       explicit s_waitcnt vmcnt(10), LDS-staged wide spike stores.

#define M_SZ 65536  // B*T
#define H_SZ 512
#define K_SZ 512
#define B_SZ 128
#define T_SZ 512
#define LSTR 132  // LDS row stride (dwords), %32==4: staging writes conflict-free

typedef __attribute__((ext_vector_type(4))) float f32x4;
typedef __attribute__((ext_vector_type(4))) unsigned int u32x4;

__device__ __forceinline__ bool detect_bf16(const unsigned int* __restrict__ w) {
  int c = 0;
#pragma unroll
  for (int i = 0; i < 64; ++i) {
    unsigned int e = (w[i] >> 7) & 0xffu;
    c += (e >= 115u && e <= 131u) ? 1 : 0;
  }
  return c > 32;  // bf16 exponents cluster in [115,131]; fp32 mantissa bits don't
}

template <bool ISB>
__device__ __forceinline__ f32x4 ld4t(const void* __restrict__ p, size_t off) {
  if constexpr (!ISB) {
    return *reinterpret_cast<const f32x4*>(reinterpret_cast<const float*>(p) + off);
  } else {
    uint2 v = *reinterpret_cast<const uint2*>(reinterpret_cast<const unsigned short*>(p) + off);
    f32x4 r;
    r.x = __uint_as_float((v.x & 0xffffu) << 16);
    r.y = __uint_as_float(v.x & 0xffff0000u);
    r.z = __uint_as_float((v.y & 0xffffu) << 16);
    r.w = __uint_as_float(v.y & 0xffff0000u);
    return r;
  }
}

template <bool ISB>
__device__ __forceinline__ float ld1t(const void* __restrict__ p, int i) {
  if constexpr (!ISB) return reinterpret_cast<const float*>(p)[i];
  return __uint_as_float((unsigned int)(reinterpret_cast<const unsigned short*>(p)[i]) << 16);
}

__device__ __forceinline__ void gl_lds16(const void* g, void* l) {
  __builtin_amdgcn_global_load_lds(
      (const __attribute__((address_space(1))) void*)g,
      (__attribute__((address_space(3))) void*)l, 16, 0, 0);
}

// ---------------- GEMM: C[m][n] = sum_k X[m][k]*W[n][k], fp32, k ascending ----
template <bool ISB>
__device__ __forceinline__ void gemm_body(const void* __restrict__ X,
                                          const void* __restrict__ Wm,
                                          float* __restrict__ C,
                                          float* __restrict__ As,
                                          float* __restrict__ Bs) {
  const int tid = threadIdx.x;
  const int r0 = tid >> 2;       // 0..63: staged row
  const int q0 = (tid & 3) * 4;  // 0,4,8,12: k-group
  const int tx = tid & 15;       // n-group
  const int ty = tid >> 4;       // m-group
  const size_t M0 = (size_t)(blockIdx.x >> 2) * 128;
  const int N0 = (blockIdx.x & 3) * 128;

  float acc[8][8];
#pragma unroll
  for (int i = 0; i < 8; ++i)
#pragma unroll
    for (int j = 0; j < 8; ++j) acc[i][j] = 0.0f;

  const size_t aoff0 = (M0 + r0) * K_SZ + q0;
  const size_t aoff1 = (M0 + r0 + 64) * K_SZ + q0;
  const size_t boff0 = (size_t)(N0 + r0) * K_SZ + q0;
  const size_t boff1 = (size_t)(N0 + r0 + 64) * K_SZ + q0;

  f32x4 pa0 = ld4t<ISB>(X, aoff0), pa1 = ld4t<ISB>(X, aoff1);
  f32x4 pb0 = ld4t<ISB>(Wm, boff0), pb1 = ld4t<ISB>(Wm, boff1);

  for (int kk = 0; kk < K_SZ; kk += 16) {
    __syncthreads();  // prior compute done -> LDS free
    As[(q0 + 0) * LSTR + r0] = pa0.x; As[(q0 + 1) * LSTR + r0] = pa0.y;
    As[(q0 + 2) * LSTR + r0] = pa0.z; As[(q0 + 3) * LSTR + r0] = pa0.w;
    As[(q0 + 0) * LSTR + r0 + 64] = pa1.x; As[(q0 + 1) * LSTR + r0 + 64] = pa1.y;
    As[(q0 + 2) * LSTR + r0 + 64] = pa1.z; As[(q0 + 3) * LSTR + r0 + 64] = pa1.w;
    Bs[(q0 + 0) * LSTR + r0] = pb0.x; Bs[(q0 + 1) * LSTR + r0] = pb0.y;
    Bs[(q0 + 2) * LSTR + r0] = pb0.z; Bs[(q0 + 3) * LSTR + r0] = pb0.w;
    Bs[(q0 + 0) * LSTR + r0 + 64] = pb1.x; Bs[(q0 + 1) * LSTR + r0 + 64] = pb1.y;
    Bs[(q0 + 2) * LSTR + r0 + 64] = pb1.z; Bs[(q0 + 3) * LSTR + r0 + 64] = pb1.w;
    __syncthreads();  // tile ready
    if (kk + 16 < K_SZ) {  // prefetch next chunk; in flight across compute
      pa0 = ld4t<ISB>(X, aoff0 + kk + 16); pa1 = ld4t<ISB>(X, aoff1 + kk + 16);
      pb0 = ld4t<ISB>(Wm, boff0 + kk + 16); pb1 = ld4t<ISB>(Wm, boff1 + kk + 16);
    }
#pragma unroll
    for (int k = 0; k < 16; ++k) {
      const f32x4 a0 = *reinterpret_cast<const f32x4*>(As + k * LSTR + ty * 4);
      const f32x4 a1 = *reinterpret_cast<const f32x4*>(As + k * LSTR + 64 + ty * 4);
      const f32x4 b0 = *reinterpret_cast<const f32x4*>(Bs + k * LSTR + tx * 4);
      const f32x4 b1 = *reinterpret_cast<const f32x4*>(Bs + k * LSTR + 64 + tx * 4);
      const float av[8] = {a0.x, a0.y, a0.z, a0.w, a1.x, a1.y, a1.z, a1.w};
      const float bv[8] = {b0.x, b0.y, b0.z, b0.w, b1.x, b1.y, b1.z, b1.w};
#pragma unroll
      for (int i = 0; i < 8; ++i)
#pragma unroll
        for (int j = 0; j < 8; ++j) acc[i][j] += av[i] * bv[j];  // contracts to FMA
    }
  }

#pragma unroll
  for (int r = 0; r < 8; ++r) {
    const size_t m = M0 + ((r < 4) ? (ty * 4 + r) : (64 + ty * 4 + (r - 4)));
    float* Cp = C + m * H_SZ + N0;
    f32x4 v0 = {acc[r][0], acc[r][1], acc[r][2], acc[r][3]};
    f32x4 v1 = {acc[r][4], acc[r][5], acc[r][6], acc[r][7]};
    __builtin_nontemporal_store(v0, reinterpret_cast<f32x4*>(Cp + tx * 4));
    __builtin_nontemporal_store(v1, reinterpret_cast<f32x4*>(Cp + 64 + tx * 4));
  }
}

__global__ __launch_bounds__(256) void sgemm_bt(const void* __restrict__ X,
                                                const void* __restrict__ Wm,
                                                float* __restrict__ C) {
  __shared__ float As[16 * LSTR];  // 8.45 KB
  __shared__ float Bs[16 * LSTR];  // 8.45 KB
  if (detect_bf16(reinterpret_cast<const unsigned int*>(X)))
    gemm_body<true>(X, Wm, C, As, Bs);
  else
    gemm_body<false>(X, Wm, C, As, Bs);
}

// ---------------- LIF scan: barrier-free wave-autonomous pipeline ------------
// Wave (b, 64-h strip); input ring 6 supergroups x 8t x 64h fp32 (12 KB/wave);
// spike stage [2][8t][64h] (4 KB/wave). Sync: explicit s_waitcnt vmcnt(10).
#define SG 8
#define NSG (T_SZ / SG)  // 64
#define RING 6           // supergroups in ring

template <bool ISB>
__device__ __forceinline__ void scan_body(
    const float* __restrict__ wx, const void* __restrict__ alpha_p,
    const void* __restrict__ beta_p, const void* __restrict__ a_p,
    const void* __restrict__ b_p, const void* __restrict__ u0p,
    const void* __restrict__ w0p, const void* __restrict__ s0p,
    void* __restrict__ out, float* __restrict__ ring, float* __restrict__ stage) {
  const int tid = threadIdx.x;
  const int wave = tid >> 6;
  const int lane = tid & 63;
  const int gw = blockIdx.x * 4 + wave;  // 0..1023
  const int b = gw >> 3;
  const int h0 = (gw & 7) * 64;
  const int h = h0 + lane;

  const float al = fminf(fmaxf(ld1t<ISB>(alpha_p, h), (float)0.8187307530779818),
                         (float)0.9607894391523232);
  const float be = fminf(fmaxf(ld1t<ISB>(beta_p, h), (float)0.9672161004820059),
                         (float)0.9917013044213351);
  const float av = fminf(fmaxf(ld1t<ISB>(a_p, h), -1.0f), 1.0f);
  const float bv = fminf(fmaxf(ld1t<ISB>(b_p, h), 0.0f), 2.0f);
  const float om = __fsub_rn(1.0f, al);

  const int bh = b * H_SZ + h;
  float u = ld1t<ISB>(u0p, bh);
  float w = ld1t<ISB>(w0p, bh);
  float s = ld1t<ISB>(s0p, bh);

  float* ring_w = ring + wave * (RING * SG * 64);   // 12 KB/wave
  float* stage_w = stage + wave * (2 * SG * 64);    // 4 KB/wave
  const float* wxb = wx + (size_t)b * T_SZ * H_SZ;  // + t*H + h

  // DMA one supergroup (8t x 64h = 2 KB) as 2 instrs of 4 t-rows each.
  // LDS dest wave-uniform base; lane i auto-writes +i*16B -> [t][64h] layout.
  auto issue_pair = [&](int g) {
    float* dst = ring_w + (g % RING) * (SG * 64);
#pragma unroll
    for (int j = 0; j < 2; ++j) {
      const int t = g * SG + j * 4 + (lane >> 4);
      gl_lds16(wxb + (size_t)t * H_SZ + h0 + (lane & 15) * 4, dst + j * 256);
    }
  };

#pragma unroll
  for (int g = 0; g < RING; ++g) issue_pair(g);  // prologue: 12 DMAs in flight

  __hip_bfloat16* outb = reinterpret_cast<__hip_bfloat16*>(out);
  float* outf = reinterpret_cast<float*>(out);

  for (int g = 0; g < NSG; ++g) {
    // Wait until pair g complete. FIFO accounting: instrs issued after pair g
    // = pairs g+1..g+5 (10) + older flush stores -> vmcnt(10) is exact at g=0
    // and conservative (never racy) for all later g.
    __builtin_amdgcn_s_waitcnt(0xF7A);  // lgkm=15, exp=7, vmcnt=10
    __builtin_amdgcn_sched_barrier(0);  // pin: no LDS reads hoist above wait

    const float* rb = ring_w + (g % RING) * (SG * 64);
    float* st = stage_w + (g & 1) * (SG * 64);
#pragma unroll
    for (int jt = 0; jt < SG; ++jt) {
      const float cur = rb[jt * 64 + lane];
      // numpy left-to-right, each op individually rounded (no FMA contraction)
      w = __fadd_rn(__fadd_rn(__fmul_rn(be, w), __fmul_rn(av, u)), __fmul_rn(bv, s));
      u = __fadd_rn(__fmul_rn(al, __fsub_rn(u, s)), __fmul_rn(om, __fsub_rn(cur, w)));
      s = (u > 1.0f) ? 1.0f : 0.0f;
      if constexpr (ISB)
        reinterpret_cast<unsigned short*>(st)[jt * 64 + lane] = (u > 1.0f) ? 0x3F80u : 0u;
      else
        st[jt * 64 + lane] = s;
    }
    // Flush supergroup's spikes with wide stores (16 B/lane).
    if constexpr (ISB) {
      const u32x4 vv = *reinterpret_cast<const u32x4*>(
          reinterpret_cast<const char*>(st) + lane * 16);
      __hip_bfloat16* gp = outb + (size_t)b * T_SZ * H_SZ +
                           (size_t)(g * SG + (lane >> 3)) * H_SZ + h0 + (lane & 7) * 8;
      __builtin_nontemporal_store(vv, reinterpret_cast<u32x4*>(gp));
    } else {
#pragma unroll
      for (int k = 0; k < 2; ++k) {
        const u32x4 vv = *reinterpret_cast<const u32x4*>(
            reinterpret_cast<const char*>(st) + k * 1024 + lane * 16);
        float* gp = outf + (size_t)b * T_SZ * H_SZ +
                    (size_t)(g * SG + k * 4 + (lane >> 4)) * H_SZ + h0 + (lane & 15) * 4;
        __builtin_nontemporal_store(vv, reinterpret_cast<u32x4*>(gp));
      }
    }
    if (g + RING < NSG) issue_pair(g + RING);
  }
}

__global__ __launch_bounds__(256) void lif_scan(
    const float* __restrict__ wx, const void* __restrict__ X,
    const void* __restrict__ alpha_p, const void* __restrict__ beta_p,
    const void* __restrict__ a_p, const void* __restrict__ b_p,
    const void* __restrict__ u0p, const void* __restrict__ w0p,
    const void* __restrict__ s0p, void* __restrict__ out) {
  __shared__ float ring[4 * RING * SG * 64];  // 48 KB
  __shared__ float stage[4 * 2 * SG * 64];    // 16 KB
  if (detect_bf16(reinterpret_cast<const unsigned int*>(X)))
    scan_body<true>(wx, alpha_p, beta_p, a_p, b_p, u0p, w0p, s0p, out, ring, stage);
  else
    scan_body<false>(wx, alpha_p, beta_p, a_p, b_p, u0p, w0p, s0p, out, ring, stage);
}

extern "C" void kernel_launch(void* const* d_in, const int* in_sizes, int n_in,
                              void* d_out, int out_size, void* d_ws, size_t ws_size,
                              hipStream_t stream) {
  const void* X = d_in[0];   // x [B,T,I]
  const void* Wm = d_in[1];  // W [H,I]
  float* ws = reinterpret_cast<float*>(d_ws);  // Wx fp32 [B,T,H]

  sgemm_bt<<<dim3((M_SZ / 128) * (H_SZ / 128)), dim3(256), 0, stream>>>(X, Wm, ws);

  lif_scan<<<dim3(256), dim3(256), 0, stream>>>(
      ws, X, d_in[2], d_in[3], d_in[4], d_in[5], d_in[6], d_in[7], d_in[8], d_out);
}